// Round 10
// baseline (121.559 us; speedup 1.0000x reference)
//
#include <hip/hip_runtime.h>
#include <hip/hip_bf16.h>
#include <math.h>

#define BATCH 16
#define SEQ 4096
#define HDIM 64

typedef __attribute__((ext_vector_type(8))) short bf16x8;   // 8 bf16 = 4 VGPR
typedef __attribute__((ext_vector_type(4))) float f32x4;
typedef __attribute__((ext_vector_type(4))) unsigned int u32x4;
typedef __attribute__((ext_vector_type(8))) unsigned short us8;

// softmax scale (1/8) * log2(e) folded into Wq -> softmax in exp2 space.
// No running max: |s| < ~25 worst case => exp2/f32 sums can't overflow.
#define QSCALE 0.1803368801111601f

static __device__ __forceinline__ float exp2_fast(float x) {
#if __has_builtin(__builtin_amdgcn_exp2f)
    return __builtin_amdgcn_exp2f(x);
#else
    float r; asm("v_exp_f32 %0, %1" : "=v"(r) : "v"(x)); return r;
#endif
}

// async global->LDS, 16B/lane. LDS dest = wave-uniform base + lane*16 (m104).
static __device__ __forceinline__ void load_lds16(const void* g, void* l) {
    __builtin_amdgcn_global_load_lds(
        (const __attribute__((address_space(1))) unsigned int*)g,
        (__attribute__((address_space(3))) unsigned int*)l,
        16, 0, 0);
}

static __device__ __forceinline__ unsigned short bf16bits(float f) {
    __hip_bfloat16 h = __float2bfloat16(f);
    return *(unsigned short*)&h;
}

// pack two fp32 -> 2x bf16 (TRUNCATION) in one v_perm_b32. Used only for P
// (softmax weights): <=2^-8 relative, mostly cancels in O/l.
static __device__ __forceinline__ unsigned int pack_bf16_trunc(float f0, float f1) {
    unsigned int u0 = __builtin_bit_cast(unsigned int, f0);
    unsigned int u1 = __builtin_bit_cast(unsigned int, f1);
#if __has_builtin(__builtin_amdgcn_perm)
    return __builtin_amdgcn_perm(u1, u0, 0x07060302u);  // sel 0-3 from arg2, 4-7 from arg1
#else
    return (u1 & 0xFFFF0000u) | (u0 >> 16);
#endif
}

// ---------------- W precompute (r20, kept) ----------------
__global__ __launch_bounds__(256)
void wconv_kernel(const float* __restrict__ Wq,
                  const float* __restrict__ Wk,
                  const float* __restrict__ Wv,
                  __hip_bfloat16* __restrict__ wsw) {
    const int mat = blockIdx.x;           // 3 blocks, one per matrix
    const int tid = threadIdx.x;
    const float* W = (mat == 0) ? Wq : (mat == 1) ? Wk : Wv;
    const float sc = (mat == 0) ? QSCALE : 1.0f;
    #pragma unroll
    for (int c2 = 0; c2 < 2; ++c2) {
        const int chunk = c2 * 256 + tid;       // [0,512)
        const int n = chunk & 63;
        const int c = chunk >> 6;               // k-chunk 0..7
        us8 u;
        #pragma unroll
        for (int j = 0; j < 8; ++j)
            u[j] = bf16bits(W[(c * 8 + j) * HDIM + n] * sc);  // RNE (runs once)
        *(us8*)(wsw + mat * 4096 + n * 64 + (size_t)(c ^ (n & 7)) * 8) = u;
    }
}

// ---------------- QKV projection (r21, kept: DMA staging, RNE x-pack) ----------------
__global__ __launch_bounds__(256)
void qkv_mfma_kernel(const float* __restrict__ x,
                     const __hip_bfloat16* __restrict__ wsw,
                     __hip_bfloat16* __restrict__ qb,
                     __hip_bfloat16* __restrict__ kb,
                     __hip_bfloat16* __restrict__ vt) {
    __shared__ __attribute__((aligned(16))) __hip_bfloat16 swt[3 * 64 * 64];   // 24 KB
    __shared__ __attribute__((aligned(16))) char spool[16384];                  // sx f32, then sout
    float* sx = (float*)spool;                                  // [64][64] f32
    __hip_bfloat16 (*sout)[80] = (__hip_bfloat16 (*)[80])spool; // [64][80] bf16

    const int tid = threadIdx.x;
    const int wv = tid >> 6;
    const int lane = tid & 63;
    const int quad = lane >> 4;
    const int ml = lane & 15;
    const size_t row0 = (size_t)blockIdx.x * 64;
    const int batch = (int)(row0 >> 12);
    const int t0 = (int)(row0 & 4095);

    // DMA: pre-swizzled W (24 KB, L2-resident) + x rows (16 KB, coalesced)
    #pragma unroll
    for (int r = 0; r < 6; ++r)
        load_lds16(wsw + (size_t)(r * 256 + tid) * 8, swt + (size_t)(r * 256 + tid) * 8);
    #pragma unroll
    for (int r = 0; r < 4; ++r)
        load_lds16(x + row0 * HDIM + (size_t)(r * 256 + tid) * 4, sx + (size_t)(r * 256 + tid) * 4);
    asm volatile("s_waitcnt vmcnt(0)" ::: "memory");
    __syncthreads();

    // A-frags from sx (rows wv*16+ml), RNE conversion
    bf16x8 a0, a1;
    {
        const float* xr = sx + (size_t)(wv * 16 + ml) * HDIM + quad * 8;
        #pragma unroll
        for (int j = 0; j < 8; ++j) a0[j] = (short)bf16bits(xr[j]);
        #pragma unroll
        for (int j = 0; j < 8; ++j) a1[j] = (short)bf16bits(xr[32 + j]);
    }
    __syncthreads();   // all waves done reading sx -> sout may overlay it

    #pragma unroll
    for (int mat = 0; mat < 3; ++mat) {
        const __hip_bfloat16* wb = swt + mat * 4096;
        f32x4 acc[4];
        #pragma unroll
        for (int nt = 0; nt < 4; ++nt) {
            const int n = nt * 16 + ml;
            const int nx = n & 7;
            const bf16x8 bl = *(const bf16x8*)(wb + (size_t)n * 64 + (size_t)((quad) ^ nx) * 8);
            const bf16x8 bh = *(const bf16x8*)(wb + (size_t)n * 64 + (size_t)((quad + 4) ^ nx) * 8);
            acc[nt] = __builtin_amdgcn_mfma_f32_16x16x32_bf16(a0, bl, (f32x4){0.f,0.f,0.f,0.f}, 0, 0, 0);
            acc[nt] = __builtin_amdgcn_mfma_f32_16x16x32_bf16(a1, bh, acc[nt], 0, 0, 0);
        }

        if (mat < 2) {
            #pragma unroll
            for (int nt = 0; nt < 4; ++nt)
                #pragma unroll
                for (int r = 0; r < 4; ++r)
                    sout[wv * 16 + quad * 4 + r][nt * 16 + ml] = __float2bfloat16(acc[nt][r]);
        } else {
            // V transpose with sigma-permuted key-columns (r12 conflict fix)
            #pragma unroll
            for (int nt = 0; nt < 4; ++nt)
                #pragma unroll
                for (int r = 0; r < 4; ++r)
                    sout[nt * 16 + ml][(wv >> 1) * 32 + quad * 8 + (wv & 1) * 4 + r] =
                        __float2bfloat16(acc[nt][r]);
        }
        __syncthreads();
        __hip_bfloat16* dst = (mat == 0) ? qb : (mat == 1) ? kb : vt;
        #pragma unroll
        for (int c2 = 0; c2 < 2; ++c2) {
            const int cc = c2 * 256 + tid;
            const int row = cc >> 3, g = cc & 7;
            us8 u = *(const us8*)&sout[row][g * 8];
            if (mat < 2)
                *(us8*)(dst + (row0 + row) * HDIM + g * 8) = u;
            else
                *(us8*)(dst + ((size_t)batch * HDIM + row) * SEQ + t0 + g * 8) = u;
        }
        __syncthreads();
    }
}

// ---------------- MFMA flash attention (r24: 128-row blocks, halved L2 staging) ----------------
// Bottleneck re-derivation: total K/V L2->LDS staging = 532 MB/launch; per
// block per tile the 16 KB DMA at a 1/4 CU L2 share (~14 B/cy) takes ~1170cy
// vs ~840cy compute -> the DMA leg, not any SQ pipe, sets the tile period.
// Explains all prior nulls (occupancy/latency attacks don't change bytes)
// and direct-V's 2x regression (MORE L2 bytes, worse transactions).
// r24: one block = 128 q-rows (8 waves = qh x mh x kh; per-wave shape and
// registers IDENTICAL to r19). Each staged K/V tile serves 2x rows ->
// staged bytes halve (266 MB); barriers per q-row halve. Waves/CU stays 16
// (2 blocks x 8). launch_bounds(512,4) keeps r19's 128-VGPR cap.
// Drain control (r18 lesson): co-resident blocks (id, id+256 -> same batch,
// same XCD) have lengths 2p+2 paired to sum 66 exactly.
// Causality: main loop t<2p mask-free for ALL waves; tile 2p uses key>q mask
// (naturally no-op for qh=1); tile 2p+1 runs on qh=1 waves only.
__global__ __launch_bounds__(512, 4)
void flash_mfma_kernel(const __hip_bfloat16* __restrict__ qb,
                       const __hip_bfloat16* __restrict__ kbuf,
                       const __hip_bfloat16* __restrict__ vt,
                       float* __restrict__ out) {
    __shared__ __attribute__((aligned(16))) __hip_bfloat16 smem[16384];  // 32 KB
    // [0,4096) k-buf0, [4096,8192) k-buf1, [8192,12288) v-buf0,
    // [12288,16384) v-buf1 (elements). Merge scratch overlays base after loop.

    const int tid = threadIdx.x;        // [0,512)
    const int wv = tid >> 6;            // 8 waves
    const int lane = tid & 63;
    const int quad = lane >> 4;
    const int ml = lane & 15;
    const int qh = wv >> 2;             // q 64-half of the 128 rows
    const int mh = (wv >> 1) & 1;       // q 32-half within it
    const int kh = wv & 1;              // key-half

    const int id = blockIdx.x;          // [0,512)
    const int b = id & 15;              // batch -> XCD pin (id%8)
    const int pp = id >> 4;             // [0,32)
    const int p = (pp < 16) ? pp : 47 - pp;   // pair: len(pp)+len(pp+16)=66
    const int qbw = p * 128 + qh * 64 + mh * 32;   // wave's first q row
    const size_t bb = (size_t)b * SEQ * HDIM;

    const __hip_bfloat16* Q = qb + bb;
    const __hip_bfloat16* K = kbuf + bb;
    const __hip_bfloat16* VT = vt + bb;   // [b][64][SEQ], key-permuted

    // Q B-frags
    bf16x8 bq[2][2];
    #pragma unroll
    for (int qi = 0; qi < 2; ++qi)
        #pragma unroll
        for (int h = 0; h < 2; ++h)
            bq[qi][h] = *(const bf16x8*)(Q + (size_t)(qbw + qi * 16 + ml) * HDIM + h * 32 + quad * 8);

    bf16x8 ones8;
    #pragma unroll
    for (int j = 0; j < 8; ++j) ones8[j] = (short)0x3F80;

    f32x4 acc[4][2];   // [d-tile][q-tile]
    #pragma unroll
    for (int nt = 0; nt < 4; ++nt)
        #pragma unroll
        for (int qi = 0; qi < 2; ++qi) acc[nt][qi] = (f32x4){0.f, 0.f, 0.f, 0.f};
    f32x4 lacc[2] = {(f32x4){0.f,0.f,0.f,0.f}, (f32x4){0.f,0.f,0.f,0.f}};

    // staging: 512 threads x 16B cover one 8 KB tile in ONE round
    const int kr = tid >> 3;
    const int kc = (tid & 7) ^ (kr & 7);
    const int dstoff = wv * 512;        // elements; HW adds lane*8

    // loop-invariant LDS fragment offsets (elements, within one 4096-el buffer)
    int koff[2][2], voff[4];
    #pragma unroll
    for (int kt = 0; kt < 2; ++kt) {
        const int row = kh * 32 + kt * 16 + ml;
        const int rb = row << 3, rxx = row & 7;
        koff[kt][0] = (rb | (quad ^ rxx)) * 8;
        koff[kt][1] = (rb | ((quad + 4) ^ rxx)) * 8;
    }
    #pragma unroll
    for (int nt = 0; nt < 4; ++nt) {
        const int row = nt * 16 + ml;
        const int rb = row << 3, rxx = row & 7;
        voff[nt] = (rb | ((kh * 4 + quad) ^ rxx)) * 8;
    }

    // prologue: stage tile 0 into buffer 0
    load_lds16(K + (size_t)kr * HDIM + kc * 8, smem + dstoff);
    load_lds16(VT + (size_t)kr * SEQ + kc * 8, smem + 8192 + dstoff);
    asm volatile("s_waitcnt vmcnt(0)" ::: "memory");
    __syncthreads();

    // ---- main loop: tiles 0..2p-1, mask-free, all 8 waves active ----
    const int nfull = 2 * p;
    for (int tile = 0; tile < nfull; ++tile) {
        const int sel = (tile & 1) * 4096;
        const int nsel = 4096 - sel;
        const __hip_bfloat16* sk = smem + sel;
        const __hip_bfloat16* sv = smem + 8192 + sel;

        // stage tile+1 (<= 2p, always a valid tile)
        const int nk = tile * 64 + 64;
        load_lds16(K + (size_t)(nk + kr) * HDIM + kc * 8, smem + nsel + dstoff);
        load_lds16(VT + (size_t)kr * SEQ + nk + kc * 8, smem + 8192 + nsel + dstoff);

        // all 8 ds_reads issued up front (V in flight during S^T)
        bf16x8 kf[2][2], va[4];
        #pragma unroll
        for (int kt = 0; kt < 2; ++kt) {
            kf[kt][0] = *(const bf16x8*)(sk + koff[kt][0]);
            kf[kt][1] = *(const bf16x8*)(sk + koff[kt][1]);
        }
        #pragma unroll
        for (int nt = 0; nt < 4; ++nt)
            va[nt] = *(const bf16x8*)(sv + voff[nt]);

        // --- S^T = K Q^T on this wave's 32 keys x 32 q's ---
        f32x4 st[2][2];
        __builtin_amdgcn_s_setprio(1);
        #pragma unroll
        for (int kt = 0; kt < 2; ++kt)
            #pragma unroll
            for (int qi = 0; qi < 2; ++qi) {
                st[kt][qi] = __builtin_amdgcn_mfma_f32_16x16x32_bf16(kf[kt][0], bq[qi][0], (f32x4){0.f,0.f,0.f,0.f}, 0, 0, 0);
                st[kt][qi] = __builtin_amdgcn_mfma_f32_16x16x32_bf16(kf[kt][1], bq[qi][1], st[kt][qi], 0, 0, 0);
            }
        __builtin_amdgcn_s_setprio(0);

        // --- qi0 softmax (VALU) ---
        bf16x8 p80;
        {
            float pv[8];
            #pragma unroll
            for (int half = 0; half < 2; ++half)
                #pragma unroll
                for (int r = 0; r < 4; ++r)
                    pv[half * 4 + r] = exp2_fast(st[half][0][r]);
            u32x4 pk;
            #pragma unroll
            for (int d = 0; d < 4; ++d)
                pk[d] = pack_bf16_trunc(pv[2 * d], pv[2 * d + 1]);
            p80 = __builtin_bit_cast(bf16x8, pk);
        }

        // --- qi0 MFMA cluster (overlaps qi1 softmax below) ---
        __builtin_amdgcn_s_setprio(1);
        lacc[0] = __builtin_amdgcn_mfma_f32_16x16x32_bf16(ones8, p80, lacc[0], 0, 0, 0);
        #pragma unroll
        for (int nt = 0; nt < 4; ++nt)
            acc[nt][0] = __builtin_amdgcn_mfma_f32_16x16x32_bf16(va[nt], p80, acc[nt][0], 0, 0, 0);
        __builtin_amdgcn_s_setprio(0);

        // --- qi1 softmax ---
        bf16x8 p81;
        {
            float pv[8];
            #pragma unroll
            for (int half = 0; half < 2; ++half)
                #pragma unroll
                for (int r = 0; r < 4; ++r)
                    pv[half * 4 + r] = exp2_fast(st[half][1][r]);
            u32x4 pk;
            #pragma unroll
            for (int d = 0; d < 4; ++d)
                pk[d] = pack_bf16_trunc(pv[2 * d], pv[2 * d + 1]);
            p81 = __builtin_bit_cast(bf16x8, pk);
        }

        // --- qi1 MFMA cluster ---
        __builtin_amdgcn_s_setprio(1);
        lacc[1] = __builtin_amdgcn_mfma_f32_16x16x32_bf16(ones8, p81, lacc[1], 0, 0, 0);
        #pragma unroll
        for (int nt = 0; nt < 4; ++nt)
            acc[nt][1] = __builtin_amdgcn_mfma_f32_16x16x32_bf16(va[nt], p81, acc[nt][1], 0, 0, 0);
        __builtin_amdgcn_s_setprio(0);

        // drain own prefetch (covered by compute), single barrier
        asm volatile("s_waitcnt vmcnt(0)" ::: "memory");
        __syncthreads();
    }

    // ---- tail tile A (tile 2p, buffer 0): diagonal for qh=0, full for qh=1;
    //      key>q mask is naturally a no-op for qh=1 waves ----
    {
        const int kb0 = nfull * 64;
        const __hip_bfloat16* sk = smem;          // buffer 0 (2p even)
        const __hip_bfloat16* sv = smem + 8192;

        // stage tail tile B (2p+1) into buffer 1
        const int nk = kb0 + 64;
        load_lds16(K + (size_t)(nk + kr) * HDIM + kc * 8, smem + 4096 + dstoff);
        load_lds16(VT + (size_t)kr * SEQ + nk + kc * 8, smem + 12288 + dstoff);

        if (!(qh == 0 && kh == 1 && mh == 0)) {   // that wave fully masked at A
            bf16x8 kf[2][2], va[4];
            #pragma unroll
            for (int kt = 0; kt < 2; ++kt) {
                kf[kt][0] = *(const bf16x8*)(sk + koff[kt][0]);
                kf[kt][1] = *(const bf16x8*)(sk + koff[kt][1]);
            }
            #pragma unroll
            for (int nt = 0; nt < 4; ++nt)
                va[nt] = *(const bf16x8*)(sv + voff[nt]);

            f32x4 st[2][2];
            #pragma unroll
            for (int kt = 0; kt < 2; ++kt)
                #pragma unroll
                for (int qi = 0; qi < 2; ++qi) {
                    st[kt][qi] = __builtin_amdgcn_mfma_f32_16x16x32_bf16(kf[kt][0], bq[qi][0], (f32x4){0.f,0.f,0.f,0.f}, 0, 0, 0);
                    st[kt][qi] = __builtin_amdgcn_mfma_f32_16x16x32_bf16(kf[kt][1], bq[qi][1], st[kt][qi], 0, 0, 0);
                }

            bf16x8 p8[2];
            #pragma unroll
            for (int qi = 0; qi < 2; ++qi) {
                const int q = qbw + qi * 16 + ml;
                float pv[8];
                #pragma unroll
                for (int half = 0; half < 2; ++half)
                    #pragma unroll
                    for (int r = 0; r < 4; ++r) {
                        const int key = kb0 + kh * 32 + half * 16 + quad * 4 + r;
                        float pval = exp2_fast(st[half][qi][r]);
                        if (key > q) pval = 0.f;
                        pv[half * 4 + r] = pval;
                    }
                u32x4 pk;
                #pragma unroll
                for (int d = 0; d < 4; ++d)
                    pk[d] = pack_bf16_trunc(pv[2 * d], pv[2 * d + 1]);
                p8[qi] = __builtin_bit_cast(bf16x8, pk);
            }

            lacc[0] = __builtin_amdgcn_mfma_f32_16x16x32_bf16(ones8, p8[0], lacc[0], 0, 0, 0);
            lacc[1] = __builtin_amdgcn_mfma_f32_16x16x32_bf16(ones8, p8[1], lacc[1], 0, 0, 0);
            #pragma unroll
            for (int nt = 0; nt < 4; ++nt) {
                acc[nt][0] = __builtin_amdgcn_mfma_f32_16x16x32_bf16(va[nt], p8[0], acc[nt][0], 0, 0, 0);
                acc[nt][1] = __builtin_amdgcn_mfma_f32_16x16x32_bf16(va[nt], p8[1], acc[nt][1], 0, 0, 0);
            }
        }
        asm volatile("s_waitcnt vmcnt(0)" ::: "memory");
        __syncthreads();
    }

    // ---- tail tile B (tile 2p+1, buffer 1): qh=1 waves only, diagonal ----
    {
        const int kb0 = nfull * 64 + 64;
        const __hip_bfloat16* sk = smem + 4096;
        const __hip_bfloat16* sv = smem + 12288;

        if (qh == 1 && !(kh == 1 && mh == 0)) {
            bf16x8 kf[2][2], va[4];
            #pragma unroll
            for (int kt = 0; kt < 2; ++kt) {
                kf[kt][0] = *(const bf16x8*)(sk + koff[kt][0]);
                kf[kt][1] = *(const bf16x8*)(sk + koff[kt][1]);
            }
            #pragma unroll
            for (int nt = 0; nt < 4; ++nt)
                va[nt] = *(const bf16x8*)(sv + voff[nt]);

            f32x4 st[2][2];
            #pragma unroll
            for (int kt = 0; kt < 2; ++kt)
                #pragma unroll
                for (int qi = 0; qi < 2; ++qi) {
                    st[kt][qi] = __builtin_amdgcn_mfma_f32_16x16x32_bf16(kf[kt][0], bq[qi][0], (f32x4){0.f,0.f,0.f,0.f}, 0, 0, 0);
                    st[kt][qi] = __builtin_amdgcn_mfma_f32_16x16x32_bf16(kf[kt][1], bq[qi][1], st[kt][qi], 0, 0, 0);
                }

            bf16x8 p8[2];
            #pragma unroll
            for (int qi = 0; qi < 2; ++qi) {
                const int q = qbw + qi * 16 + ml;
                float pv[8];
                #pragma unroll
                for (int half = 0; half < 2; ++half)
                    #pragma unroll
                    for (int r = 0; r < 4; ++r) {
                        const int key = kb0 + kh * 32 + half * 16 + quad * 4 + r;
                        float pval = exp2_fast(st[half][qi][r]);
                        if (key > q) pval = 0.f;
                        pv[half * 4 + r] = pval;
                    }
                u32x4 pk;
                #pragma unroll
                for (int d = 0; d < 4; ++d)
                    pk[d] = pack_bf16_trunc(pv[2 * d], pv[2 * d + 1]);
                p8[qi] = __builtin_bit_cast(bf16x8, pk);
            }

            lacc[0] = __builtin_amdgcn_mfma_f32_16x16x32_bf16(ones8, p8[0], lacc[0], 0, 0, 0);
            lacc[1] = __builtin_amdgcn_mfma_f32_16x16x32_bf16(ones8, p8[1], lacc[1], 0, 0, 0);
            #pragma unroll
            for (int nt = 0; nt < 4; ++nt) {
                acc[nt][0] = __builtin_amdgcn_mfma_f32_16x16x32_bf16(va[nt], p8[0], acc[nt][0], 0, 0, 0);
                acc[nt][1] = __builtin_amdgcn_mfma_f32_16x16x32_bf16(va[nt], p8[1], acc[nt][1], 0, 0, 0);
            }
        }
    }

    // ---- merge kh=1 partials into kh=0 (scratch overlays staging bufs;
    // first __syncthreads orders tail reads before scratch writes) ----
    float (*smerge)[64][18] = (float (*)[64][18])smem;   // [qh*2+mh][64][18]
    const int pid = wv >> 1;    // (qh,mh) pair id; partner differs only in kh
    #pragma unroll
    for (int qi = 0; qi < 2; ++qi) {
        __syncthreads();
        if (kh == 1) {
            float* mrow = smerge[pid][lane];
            #pragma unroll
            for (int nt = 0; nt < 4; ++nt)
                #pragma unroll
                for (int r = 0; r < 4; ++r) mrow[nt * 4 + r] = acc[nt][qi][r];
            mrow[16] = lacc[qi][0];
        }
        __syncthreads();
        if (kh == 0) {
            const float* mrow = smerge[pid][lane];
            const float inv = 1.0f / (lacc[qi][0] + mrow[16]);
            float* orow = out + bb + (size_t)(qbw + qi * 16 + ml) * HDIM;
            #pragma unroll
            for (int nt = 0; nt < 4; ++nt) {
                float4 o;
                o.x = (acc[nt][qi][0] + mrow[nt * 4 + 0]) * inv;
                o.y = (acc[nt][qi][1] + mrow[nt * 4 + 1]) * inv;
                o.z = (acc[nt][qi][2] + mrow[nt * 4 + 2]) * inv;
                o.w = (acc[nt][qi][3] + mrow[nt * 4 + 3]) * inv;
                *(float4*)(orow + nt * 16 + quad * 4) = o;
            }
        }
    }
}

extern "C" void kernel_launch(void* const* d_in, const int* in_sizes, int n_in,
                              void* d_out, int out_size, void* d_ws, size_t ws_size,
                              hipStream_t stream) {
    const float* x  = (const float*)d_in[0];
    const float* Wq = (const float*)d_in[1];
    const float* Wk = (const float*)d_in[2];
    const float* Wv = (const float*)d_in[3];
    float* outp = (float*)d_out;

    const size_t elems = (size_t)BATCH * SEQ * HDIM;
    __hip_bfloat16* qb = (__hip_bfloat16*)d_ws;           // 8 MB
    __hip_bfloat16* kb = qb + elems;                      // 8 MB
    __hip_bfloat16* vt = kb + elems;                      // 8 MB, [b][d][t] key-permuted
    __hip_bfloat16* wsw = vt + elems;                     // 24 KB pre-swizzled bf16 W

    wconv_kernel<<<dim3(3), 256, 0, stream>>>(Wq, Wk, Wv, wsw);
    qkv_mfma_kernel<<<dim3(BATCH * SEQ / 64), 256, 0, stream>>>(x, wsw, qb, kb, vt);
    // 512 blocks x 512 threads: 16 batches x 32 q-pairs of 128 rows
    flash_mfma_kernel<<<dim3(BATCH * SEQ / 128), 512, 0, stream>>>(qb, kb, vt, outp);
}

// Round 11
// 116.798 us; speedup vs baseline: 1.0408x; 1.0408x over previous
//
#include <hip/hip_runtime.h>
#include <hip/hip_bf16.h>
#include <math.h>

#define BATCH 16
#define SEQ 4096
#define HDIM 64

typedef __attribute__((ext_vector_type(8))) short bf16x8;   // 8 bf16 = 4 VGPR
typedef __attribute__((ext_vector_type(4))) float f32x4;
typedef __attribute__((ext_vector_type(4))) unsigned int u32x4;
typedef __attribute__((ext_vector_type(8))) unsigned short us8;

// softmax scale (1/8) * log2(e) folded into Wq -> softmax in exp2 space.
// No running max: |s| < ~25 worst case => exp2/f32 sums can't overflow.
#define QSCALE 0.1803368801111601f

static __device__ __forceinline__ float exp2_fast(float x) {
#if __has_builtin(__builtin_amdgcn_exp2f)
    return __builtin_amdgcn_exp2f(x);
#else
    float r; asm("v_exp_f32 %0, %1" : "=v"(r) : "v"(x)); return r;
#endif
}

// async global->LDS, 16B/lane. LDS dest = wave-uniform base + lane*16 (m104).
static __device__ __forceinline__ void load_lds16(const void* g, void* l) {
    __builtin_amdgcn_global_load_lds(
        (const __attribute__((address_space(1))) unsigned int*)g,
        (__attribute__((address_space(3))) unsigned int*)l,
        16, 0, 0);
}

static __device__ __forceinline__ unsigned short bf16bits(float f) {
    __hip_bfloat16 h = __float2bfloat16(f);
    return *(unsigned short*)&h;
}

// pack two fp32 -> 2x bf16 (TRUNCATION, not RNE) in one v_perm_b32:
// result low16 = hi16(f0), high16 = hi16(f1). Used only for P (softmax
// weights): <=2^-8 relative, mostly cancels in O/l; absmax slack is 4.5x.
static __device__ __forceinline__ unsigned int pack_bf16_trunc(float f0, float f1) {
    unsigned int u0 = __builtin_bit_cast(unsigned int, f0);
    unsigned int u1 = __builtin_bit_cast(unsigned int, f1);
#if __has_builtin(__builtin_amdgcn_perm)
    return __builtin_amdgcn_perm(u1, u0, 0x07060302u);  // sel 0-3 from arg2, 4-7 from arg1
#else
    return (u1 & 0xFFFF0000u) | (u0 >> 16);
#endif
}

// ---------------- QKV projection (round-5 proven version) ----------------
__global__ __launch_bounds__(256)
void qkv_mfma_kernel(const float* __restrict__ x,
                     const float* __restrict__ Wq,
                     const float* __restrict__ Wk,
                     const float* __restrict__ Wv,
                     __hip_bfloat16* __restrict__ qb,
                     __hip_bfloat16* __restrict__ kb,
                     __hip_bfloat16* __restrict__ vt) {
    __shared__ __attribute__((aligned(16))) __hip_bfloat16 swt[3 * 64 * 64];   // 24 KB
    __shared__ __attribute__((aligned(16))) __hip_bfloat16 sout[64][80];       // 10.2 KB
    const int tid = threadIdx.x;
    const int wv = tid >> 6;
    const int lane = tid & 63;
    const int quad = lane >> 4;
    const int ml = lane & 15;
    const size_t row0 = (size_t)blockIdx.x * 64;
    const int batch = (int)(row0 >> 12);
    const int t0 = (int)(row0 & 4095);

    // W -> swt (XOR-swizzled [mat][n][k]); chunk-owner fill, b128 writes.
    #pragma unroll
    for (int mat = 0; mat < 3; ++mat) {
        const float* W = (mat == 0) ? Wq : (mat == 1) ? Wk : Wv;
        const float sc = (mat == 0) ? QSCALE : 1.0f;
        #pragma unroll
        for (int c2 = 0; c2 < 2; ++c2) {
            const int chunk = c2 * 256 + tid;       // [0,512)
            const int n = chunk & 63;
            const int c = chunk >> 6;               // k-chunk 0..7
            us8 u;
            #pragma unroll
            for (int j = 0; j < 8; ++j)
                u[j] = bf16bits(W[(c * 8 + j) * HDIM + n] * sc);  // 256B-coalesced reads
            *(us8*)(swt + mat * 4096 + n * 64 + (size_t)(c ^ (n & 7)) * 8) = u;
        }
    }

    // A-frags directly from global x (rows wv*16+ml)
    bf16x8 a0, a1;
    {
        const float4* xr = (const float4*)(x + (row0 + wv * 16 + ml) * HDIM);
        float4 lo = xr[quad * 2], hi = xr[quad * 2 + 1];
        float t8[8] = {lo.x, lo.y, lo.z, lo.w, hi.x, hi.y, hi.z, hi.w};
        #pragma unroll
        for (int j = 0; j < 8; ++j) a0[j] = (short)bf16bits(t8[j]);
        lo = xr[8 + quad * 2]; hi = xr[9 + quad * 2];
        float u8[8] = {lo.x, lo.y, lo.z, lo.w, hi.x, hi.y, hi.z, hi.w};
        #pragma unroll
        for (int j = 0; j < 8; ++j) a1[j] = (short)bf16bits(u8[j]);
    }
    __syncthreads();   // swt ready

    #pragma unroll
    for (int mat = 0; mat < 3; ++mat) {
        const __hip_bfloat16* wb = swt + mat * 4096;
        f32x4 acc[4];
        #pragma unroll
        for (int nt = 0; nt < 4; ++nt) {
            const int n = nt * 16 + ml;
            const int nx = n & 7;
            const bf16x8 bl = *(const bf16x8*)(wb + (size_t)n * 64 + (size_t)((quad) ^ nx) * 8);
            const bf16x8 bh = *(const bf16x8*)(wb + (size_t)n * 64 + (size_t)((quad + 4) ^ nx) * 8);
            acc[nt] = __builtin_amdgcn_mfma_f32_16x16x32_bf16(a0, bl, (f32x4){0.f,0.f,0.f,0.f}, 0, 0, 0);
            acc[nt] = __builtin_amdgcn_mfma_f32_16x16x32_bf16(a1, bh, acc[nt], 0, 0, 0);
        }

        if (mat < 2) {
            #pragma unroll
            for (int nt = 0; nt < 4; ++nt)
                #pragma unroll
                for (int r = 0; r < 4; ++r)
                    sout[wv * 16 + quad * 4 + r][nt * 16 + ml] = __float2bfloat16(acc[nt][r]);
        } else {
            // V transpose with sigma-permuted key-columns (r12 conflict fix)
            #pragma unroll
            for (int nt = 0; nt < 4; ++nt)
                #pragma unroll
                for (int r = 0; r < 4; ++r)
                    sout[nt * 16 + ml][(wv >> 1) * 32 + quad * 8 + (wv & 1) * 4 + r] =
                        __float2bfloat16(acc[nt][r]);
        }
        __syncthreads();
        __hip_bfloat16* dst = (mat == 0) ? qb : (mat == 1) ? kb : vt;
        #pragma unroll
        for (int c2 = 0; c2 < 2; ++c2) {
            const int cc = c2 * 256 + tid;
            const int row = cc >> 3, g = cc & 7;
            us8 u = *(const us8*)&sout[row][g * 8];
            if (mat < 2)
                *(us8*)(dst + (row0 + row) * HDIM + g * 8) = u;
            else
                *(us8*)(dst + ((size_t)batch * HDIM + row) * SEQ + t0 + g * 8) = u;
        }
        __syncthreads();
    }
}

// ---------------- MFMA flash attention (r25 = r19 best-known + staging strength-reduction) ----------------
// r24 (128-row blocks) reverted: halved L2 staging bytes, time went UP ->
// L2-BW theory falsified (achieved ~20 B/cy vs ~56 ceiling; never bound).
// Nine structural attacks, one win (r19). This round: restore the proven
// 45.5us r19 structure; only change is running-pointer staging addresses
// (4x 64-bit addr chains -> 4 pointer increments), trimming the measured
// max pipe (VALU 43%). Pre-commit: if total lands >=117, declare converged.
__global__ __launch_bounds__(256, 4)
void flash_mfma_kernel(const __hip_bfloat16* __restrict__ qb,
                       const __hip_bfloat16* __restrict__ kbuf,
                       const __hip_bfloat16* __restrict__ vt,
                       float* __restrict__ out) {
    __shared__ __attribute__((aligned(16))) __hip_bfloat16 smem[16384];  // 32 KB
    // [0,4096) k-buf0, [4096,8192) k-buf1, [8192,12288) v-buf0,
    // [12288,16384) v-buf1 (elements). Merge scratch overlays base after loop.

    const int tid = threadIdx.x;
    const int wv = tid >> 6;
    const int lane = tid & 63;
    const int quad = lane >> 4;
    const int ml = lane & 15;
    const int mh = wv & 1;          // q-half
    const int kh = wv >> 1;         // key-half

    const int id = blockIdx.x;
    const int b = id & 15;          // id%8 pins batch->XCD
    const int t = id >> 4;
    const int hi2 = t >> 4, mid = t & 15;
    const int qt = (hi2 == 0) ? (63 - mid)
                 : (hi2 == 1) ? (32 + mid)
                 : (hi2 == 2) ? (31 - mid) : mid;
    const int qbw = qt * 64 + mh * 32;    // wave's first q row
    const size_t bb = (size_t)b * SEQ * HDIM;

    const __hip_bfloat16* Q = qb + bb;
    const __hip_bfloat16* K = kbuf + bb;
    const __hip_bfloat16* VT = vt + bb;   // [b][64][SEQ], key-permuted

    // Q B-frags
    bf16x8 bq[2][2];
    #pragma unroll
    for (int qi = 0; qi < 2; ++qi)
        #pragma unroll
        for (int h = 0; h < 2; ++h)
            bq[qi][h] = *(const bf16x8*)(Q + (size_t)(qbw + qi * 16 + ml) * HDIM + h * 32 + quad * 8);

    bf16x8 ones8;
    #pragma unroll
    for (int j = 0; j < 8; ++j) ones8[j] = (short)0x3F80;

    f32x4 acc[4][2];   // [d-tile][q-tile]
    #pragma unroll
    for (int nt = 0; nt < 4; ++nt)
        #pragma unroll
        for (int qi = 0; qi < 2; ++qi) acc[nt][qi] = (f32x4){0.f, 0.f, 0.f, 0.f};
    f32x4 lacc[2] = {(f32x4){0.f,0.f,0.f,0.f}, (f32x4){0.f,0.f,0.f,0.f}};

    // staging geometry: 2 rounds x 64 lanes per wave, XOR chunk swizzle
    const int s0 = wv * 128 + lane;
    const int s1 = s0 + 64;
    const int r0row = s0 >> 3, r0ch = (s0 & 7) ^ (r0row & 7);
    const int r1row = s1 >> 3, r1ch = (s1 & 7) ^ (r1row & 7);
    const int d0 = (wv * 128) * 8;
    const int d1 = (wv * 128 + 64) * 8;

    // loop-invariant LDS fragment offsets (elements)
    int koff[2][2], voff[4];
    #pragma unroll
    for (int kt = 0; kt < 2; ++kt) {
        const int row = kh * 32 + kt * 16 + ml;
        const int rb = row << 3, rxx = row & 7;
        koff[kt][0] = (rb | (quad ^ rxx)) * 8;
        koff[kt][1] = (rb | ((quad + 4) ^ rxx)) * 8;
    }
    #pragma unroll
    for (int nt = 0; nt < 4; ++nt) {
        const int row = nt * 16 + ml;
        const int rb = row << 3, rxx = row & 7;
        voff[nt] = (rb | ((kh * 4 + quad) ^ rxx)) * 8;
    }

    // prologue: stage tile 0 into buffer 0
    load_lds16(K + (size_t)r0row * HDIM + r0ch * 8, smem + d0);
    load_lds16(K + (size_t)r1row * HDIM + r1ch * 8, smem + d1);
    load_lds16(VT + (size_t)r0row * SEQ + r0ch * 8, smem + 8192 + d0);
    load_lds16(VT + (size_t)r1row * SEQ + r1ch * 8, smem + 8192 + d1);
    asm volatile("s_waitcnt vmcnt(0)" ::: "memory");
    __syncthreads();

    // running staging pointers for tile+1 (strength-reduced: +8KB / +128B per tile)
    const __hip_bfloat16* kg0 = K + (size_t)(64 + r0row) * HDIM + r0ch * 8;
    const __hip_bfloat16* kg1 = K + (size_t)(64 + r1row) * HDIM + r1ch * 8;
    const __hip_bfloat16* vg0 = VT + (size_t)r0row * SEQ + 64 + r0ch * 8;
    const __hip_bfloat16* vg1 = VT + (size_t)r1row * SEQ + 64 + r1ch * 8;

    // ---- main loop: full tiles only (no mask, no wave-skip, all active) ----
    for (int tile = 0; tile < qt; ++tile) {
        const int sel = (tile & 1) * 4096;
        const int nsel = 4096 - sel;
        const __hip_bfloat16* sk = smem + sel;
        const __hip_bfloat16* sv = smem + 8192 + sel;

        // issue staging of tile+1 (always valid: tile+1 <= qt)
        load_lds16(kg0, smem + nsel + d0);
        load_lds16(kg1, smem + nsel + d1);
        load_lds16(vg0, smem + 8192 + nsel + d0);
        load_lds16(vg1, smem + 8192 + nsel + d1);
        kg0 += 64 * HDIM; kg1 += 64 * HDIM;
        vg0 += 64; vg1 += 64;

        // all 8 ds_reads issued up front (V in flight during S^T)
        bf16x8 kf[2][2], va[4];
        #pragma unroll
        for (int kt = 0; kt < 2; ++kt) {
            kf[kt][0] = *(const bf16x8*)(sk + koff[kt][0]);
            kf[kt][1] = *(const bf16x8*)(sk + koff[kt][1]);
        }
        #pragma unroll
        for (int nt = 0; nt < 4; ++nt)
            va[nt] = *(const bf16x8*)(sv + voff[nt]);

        // --- S^T = K Q^T on this wave's 32 keys x 32 q's ---
        f32x4 st[2][2];
        __builtin_amdgcn_s_setprio(1);
        #pragma unroll
        for (int kt = 0; kt < 2; ++kt)
            #pragma unroll
            for (int qi = 0; qi < 2; ++qi) {
                st[kt][qi] = __builtin_amdgcn_mfma_f32_16x16x32_bf16(kf[kt][0], bq[qi][0], (f32x4){0.f,0.f,0.f,0.f}, 0, 0, 0);
                st[kt][qi] = __builtin_amdgcn_mfma_f32_16x16x32_bf16(kf[kt][1], bq[qi][1], st[kt][qi], 0, 0, 0);
            }
        __builtin_amdgcn_s_setprio(0);

        // --- qi0 softmax (VALU) ---
        bf16x8 p80;
        {
            float pv[8];
            #pragma unroll
            for (int half = 0; half < 2; ++half)
                #pragma unroll
                for (int r = 0; r < 4; ++r)
                    pv[half * 4 + r] = exp2_fast(st[half][0][r]);
            u32x4 pk;
            #pragma unroll
            for (int d = 0; d < 4; ++d)
                pk[d] = pack_bf16_trunc(pv[2 * d], pv[2 * d + 1]);
            p80 = __builtin_bit_cast(bf16x8, pk);
        }

        // --- qi0 MFMA cluster (overlaps qi1 softmax below) ---
        __builtin_amdgcn_s_setprio(1);
        lacc[0] = __builtin_amdgcn_mfma_f32_16x16x32_bf16(ones8, p80, lacc[0], 0, 0, 0);
        #pragma unroll
        for (int nt = 0; nt < 4; ++nt)
            acc[nt][0] = __builtin_amdgcn_mfma_f32_16x16x32_bf16(va[nt], p80, acc[nt][0], 0, 0, 0);
        __builtin_amdgcn_s_setprio(0);

        // --- qi1 softmax (VALU, independent of the qi0 cluster above) ---
        bf16x8 p81;
        {
            float pv[8];
            #pragma unroll
            for (int half = 0; half < 2; ++half)
                #pragma unroll
                for (int r = 0; r < 4; ++r)
                    pv[half * 4 + r] = exp2_fast(st[half][1][r]);
            u32x4 pk;
            #pragma unroll
            for (int d = 0; d < 4; ++d)
                pk[d] = pack_bf16_trunc(pv[2 * d], pv[2 * d + 1]);
            p81 = __builtin_bit_cast(bf16x8, pk);
        }

        // --- qi1 MFMA cluster ---
        __builtin_amdgcn_s_setprio(1);
        lacc[1] = __builtin_amdgcn_mfma_f32_16x16x32_bf16(ones8, p81, lacc[1], 0, 0, 0);
        #pragma unroll
        for (int nt = 0; nt < 4; ++nt)
            acc[nt][1] = __builtin_amdgcn_mfma_f32_16x16x32_bf16(va[nt], p81, acc[nt][1], 0, 0, 0);
        __builtin_amdgcn_s_setprio(0);

        // drain own prefetch (covered by the compute phase), single barrier
        asm volatile("s_waitcnt vmcnt(0)" ::: "memory");
        __syncthreads();
    }

    // ---- peeled diagonal tile (tile == qt): mask + wave-skip live here ----
    {
        const int kb0 = qt * 64;
        const int sel = (qt & 1) * 4096;
        const __hip_bfloat16* sk = smem + sel;
        const __hip_bfloat16* sv = smem + 8192 + sel;

        if (!(kh == 1 && mh == 0)) {   // that wave is fully masked
            bf16x8 kf[2][2], va[4];
            #pragma unroll
            for (int kt = 0; kt < 2; ++kt) {
                kf[kt][0] = *(const bf16x8*)(sk + koff[kt][0]);
                kf[kt][1] = *(const bf16x8*)(sk + koff[kt][1]);
            }
            #pragma unroll
            for (int nt = 0; nt < 4; ++nt)
                va[nt] = *(const bf16x8*)(sv + voff[nt]);

            f32x4 st[2][2];
            #pragma unroll
            for (int kt = 0; kt < 2; ++kt)
                #pragma unroll
                for (int qi = 0; qi < 2; ++qi) {
                    st[kt][qi] = __builtin_amdgcn_mfma_f32_16x16x32_bf16(kf[kt][0], bq[qi][0], (f32x4){0.f,0.f,0.f,0.f}, 0, 0, 0);
                    st[kt][qi] = __builtin_amdgcn_mfma_f32_16x16x32_bf16(kf[kt][1], bq[qi][1], st[kt][qi], 0, 0, 0);
                }

            bf16x8 p8[2];
            #pragma unroll
            for (int qi = 0; qi < 2; ++qi) {
                const int q = qbw + qi * 16 + ml;
                float pv[8];
                #pragma unroll
                for (int half = 0; half < 2; ++half)
                    #pragma unroll
                    for (int r = 0; r < 4; ++r) {
                        const int key = kb0 + kh * 32 + half * 16 + quad * 4 + r;
                        float pval = exp2_fast(st[half][qi][r]);
                        if (key > q) pval = 0.f;
                        pv[half * 4 + r] = pval;
                    }
                u32x4 pk;
                #pragma unroll
                for (int d = 0; d < 4; ++d)
                    pk[d] = pack_bf16_trunc(pv[2 * d], pv[2 * d + 1]);
                p8[qi] = __builtin_bit_cast(bf16x8, pk);
            }

            lacc[0] = __builtin_amdgcn_mfma_f32_16x16x32_bf16(ones8, p8[0], lacc[0], 0, 0, 0);
            lacc[1] = __builtin_amdgcn_mfma_f32_16x16x32_bf16(ones8, p8[1], lacc[1], 0, 0, 0);
            #pragma unroll
            for (int nt = 0; nt < 4; ++nt) {
                acc[nt][0] = __builtin_amdgcn_mfma_f32_16x16x32_bf16(va[nt], p8[0], acc[nt][0], 0, 0, 0);
                acc[nt][1] = __builtin_amdgcn_mfma_f32_16x16x32_bf16(va[nt], p8[1], acc[nt][1], 0, 0, 0);
            }
        }
    }

    // ---- merge kh=1 partials into kh=0 (scratch overlays staging bufs;
    // first __syncthreads orders peel reads before scratch writes) ----
    float (*smerge)[64][18] = (float (*)[64][18])smem;
    #pragma unroll
    for (int qi = 0; qi < 2; ++qi) {
        __syncthreads();
        if (kh == 1) {
            float* mrow = smerge[mh][lane];
            #pragma unroll
            for (int nt = 0; nt < 4; ++nt)
                #pragma unroll
                for (int r = 0; r < 4; ++r) mrow[nt * 4 + r] = acc[nt][qi][r];
            mrow[16] = lacc[qi][0];
        }
        __syncthreads();
        if (kh == 0) {
            const float* mrow = smerge[mh][lane];
            const float inv = 1.0f / (lacc[qi][0] + mrow[16]);
            float* orow = out + bb + (size_t)(qbw + qi * 16 + ml) * HDIM;
            #pragma unroll
            for (int nt = 0; nt < 4; ++nt) {
                float4 o;
                o.x = (acc[nt][qi][0] + mrow[nt * 4 + 0]) * inv;
                o.y = (acc[nt][qi][1] + mrow[nt * 4 + 1]) * inv;
                o.z = (acc[nt][qi][2] + mrow[nt * 4 + 2]) * inv;
                o.w = (acc[nt][qi][3] + mrow[nt * 4 + 3]) * inv;
                *(float4*)(orow + nt * 16 + quad * 4) = o;
            }
        }
    }
}

extern "C" void kernel_launch(void* const* d_in, const int* in_sizes, int n_in,
                              void* d_out, int out_size, void* d_ws, size_t ws_size,
                              hipStream_t stream) {
    const float* x  = (const float*)d_in[0];
    const float* Wq = (const float*)d_in[1];
    const float* Wk = (const float*)d_in[2];
    const float* Wv = (const float*)d_in[3];
    float* outp = (float*)d_out;

    const size_t elems = (size_t)BATCH * SEQ * HDIM;
    __hip_bfloat16* qb = (__hip_bfloat16*)d_ws;           // 8 MB
    __hip_bfloat16* kb = qb + elems;                      // 8 MB
    __hip_bfloat16* vt = kb + elems;                      // 8 MB, [b][d][t] key-permuted

    qkv_mfma_kernel<<<dim3(BATCH * SEQ / 64), 256, 0, stream>>>(x, Wq, Wk, Wv, qb, kb, vt);
    flash_mfma_kernel<<<dim3(BATCH * SEQ / 64), 256, 0, stream>>>(qb, kb, vt, outp);
}